// Round 6
// baseline (1862.130 us; speedup 1.0000x reference)
//
#include <hip/hip_runtime.h>
#include <hip/hip_bf16.h>
#include <hip/hip_fp16.h>

// Problem constants
#define BB 64
#define SS 512
#define HH 512
#define EE 512

typedef _Float16 h2 __attribute__((ext_vector_type(2)));
typedef _Float16 f16x8 __attribute__((ext_vector_type(8)));
typedef float f32x4 __attribute__((ext_vector_type(4)));

static __device__ inline h2 bch2(unsigned int x) {
  return __builtin_bit_cast(h2, x);
}

static __device__ inline float dot2f(h2 a, h2 b, float c) {
#if __has_builtin(__builtin_amdgcn_fdot2)
  return __builtin_amdgcn_fdot2(a, b, c, false);
#else
  return c + (float)a[0] * (float)b[0] + (float)a[1] * (float)b[1];
#endif
}

static __device__ inline float tanhf_fast(float x) {
  float e = __expf(2.0f * x);
  return 1.0f - 2.0f / (e + 1.0f);
}

static __device__ inline f16x8 cvt8(float4 f0, float4 f1) {
  return (f16x8){(_Float16)f0.x, (_Float16)f0.y, (_Float16)f0.z, (_Float16)f0.w,
                 (_Float16)f1.x, (_Float16)f1.y, (_Float16)f1.z, (_Float16)f1.w};
}

// ---------------------------------------------------------------------------
// MFMA GEMM: out[m][n] = sum_k A[m][k]*W[n][k] + bias0[n] + bias1[n]
// W-panel [128 n][512 k] f16 resident in LDS (XOR-swizzled, staged once).
// A streamed from global: GATHER -> emb[tokens[m]] f32 (cvt f16), else f16.
// Grid: (M/512, 512/128) = (64, 4); 256 thr = 4 waves; wave owns 128 M-rows.
// ---------------------------------------------------------------------------
template <bool GATHER>
__global__ __launch_bounds__(256) void gemm_mfma(
    const _Float16* __restrict__ Af16, const int* __restrict__ tokens,
    const float* __restrict__ emb, const float* __restrict__ W,
    const float* __restrict__ bias0, const float* __restrict__ bias1,
    float* __restrict__ out) {
  __shared__ f16x8 wlds[128 * 64];  // [n_loc][slot], slot=(k/8)^(n_loc&7); 128KB
  const int tid = threadIdx.x;
  const int mg = blockIdx.x;       // 64 M-groups of 512 rows
  const int n0 = blockIdx.y * 128; // 4 N-groups

  // ---- stage W panel (f32 -> f16, swizzled) ----
  {
    const int n_loc = tid >> 1;  // 0..127
    const int kh = tid & 1;      // k half (256 each)
    const float4* wrow = (const float4*)(W + (long)(n0 + n_loc) * HH + kh * 256);
#pragma unroll
    for (int i = 0; i < 32; ++i) {
      f16x8 v = cvt8(wrow[2 * i], wrow[2 * i + 1]);
      const int slog = kh * 32 + i;
      wlds[n_loc * 64 + (slog ^ (n_loc & 7))] = v;
    }
  }
  __syncthreads();

  const int w = tid >> 6;
  const int l = tid & 63;
  const int lr = l & 15;
  const int cg = l >> 4;

  float bsum[8];
#pragma unroll
  for (int nt = 0; nt < 8; ++nt) {
    const int n = n0 + nt * 16 + lr;
    bsum[nt] = bias0[n] + bias1[n];
  }

  for (int mt = 0; mt < 8; ++mt) {
    const int m0 = mg * 512 + w * 128 + mt * 16;
    const int row = m0 + lr;
    const float* arow_f32 = nullptr;
    const _Float16* arow_f16 = nullptr;
    if constexpr (GATHER) {
      arow_f32 = emb + (long)tokens[row] * EE;
    } else {
      arow_f16 = Af16 + (long)row * HH;
    }

    f32x4 acc[8] = {{0.f, 0.f, 0.f, 0.f}, {0.f, 0.f, 0.f, 0.f},
                    {0.f, 0.f, 0.f, 0.f}, {0.f, 0.f, 0.f, 0.f},
                    {0.f, 0.f, 0.f, 0.f}, {0.f, 0.f, 0.f, 0.f},
                    {0.f, 0.f, 0.f, 0.f}, {0.f, 0.f, 0.f, 0.f}};
#pragma unroll
    for (int kt = 0; kt < 16; ++kt) {
      f16x8 af;
      if constexpr (GATHER) {
        const float4* p = (const float4*)(arow_f32 + kt * 32 + cg * 8);
        af = cvt8(p[0], p[1]);
      } else {
        af = *(const f16x8*)(arow_f16 + kt * 32 + cg * 8);
      }
#pragma unroll
      for (int nt = 0; nt < 8; ++nt) {
        f16x8 bf = wlds[(nt * 16 + lr) * 64 + ((kt * 4 + cg) ^ (lr & 7))];
        acc[nt] = __builtin_amdgcn_mfma_f32_16x16x32_f16(af, bf, acc[nt], 0, 0, 0);
      }
    }
#pragma unroll
    for (int nt = 0; nt < 8; ++nt) {
      const int n = n0 + nt * 16 + lr;
#pragma unroll
      for (int j = 0; j < 4; ++j) {
        const int m = m0 + cg * 4 + j;
        out[(long)m * HH + n] = acc[nt][j] + bsum[nt];
      }
    }
  }
}

// ---------------------------------------------------------------------------
// Recurrence: h_t = tanh(xw_t + W_hh h_{t-1}). One wg / batch elem, 512 thr =
// 1 thr per output row. W row r: cols [0,416) as 208 h2 in regs (VGPR+AGPR),
// cols [416,512) as 12 uint4 chunks in LDS (96KB). All LDS data is loaded as
// uint4 and fed to v_dot2 via 32-bit bit_cast so each operand IS the load
// result register (no shufflevector extraction instructions — round-5 showed
// ~300 phantom VALU instrs/step from f16x8 sub-vector extracts).
// h_{t-1} double-buffered in LDS f16; hout store deferred into next step's
// compute shadow; xw prefetched 1 step ahead.
// ---------------------------------------------------------------------------
__global__ __launch_bounds__(512, 2) void rec_v4(
    const float* __restrict__ Whh,  // [512][512] f32
    const float* __restrict__ xw,   // [B*S][512] f32
    _Float16* __restrict__ hout     // [B*S][512] f16
) {
  extern __shared__ char smem[];
  uint4* wlds = (uint4*)smem;                        // [12][512] = 96KB
  _Float16* hs = (_Float16*)(smem + 12 * 512 * 16);  // [2][512] f16

  const int b = blockIdx.x;
  const int r = threadIdx.x;
  const long base = (long)b * SS;

  // ---- setup ----
  h2 w[208];
  {
    const float2* wrow2 = (const float2*)(Whh + (long)r * HH);
#pragma unroll
    for (int q = 0; q < 208; ++q) {
      float2 f = wrow2[q];
      h2 v;
      v[0] = (_Float16)f.x;
      v[1] = (_Float16)f.y;
      w[q] = v;
    }
    const float4* wrow4 = (const float4*)(Whh + (long)r * HH + 416);
#pragma unroll
    for (int s = 0; s < 12; ++s)
      wlds[s * 512 + r] =
          __builtin_bit_cast(uint4, cvt8(wrow4[2 * s], wrow4[2 * s + 1]));
  }
  hs[r] = (_Float16)0.f;  // h_{-1} = 0 in buffer 0
  __syncthreads();

  float xwv = xw[base * HH + r];
  float hval_prev = 0.f;

  for (int t = 0; t < SS; ++t) {
    // deferred hout store for t-1 (drains during this step's compute)
    if (t > 0) hout[(base + t - 1) * HH + r] = (_Float16)hval_prev;
    // prefetch next step's xw
    float xw_next = (t + 1 < SS) ? xw[(base + t + 1) * HH + r] : 0.f;

    const uint4* hb = (const uint4*)(hs + (t & 1) * 512);
    float a0 = 0.f, a1 = 0.f, a2 = 0.f, a3 = 0.f;
#pragma unroll
    for (int j = 0; j < 52; ++j) {  // cols [0,416): W in regs, h broadcast
      uint4 u = hb[j];
      a0 = dot2f(w[4 * j + 0], bch2(u.x), a0);
      a1 = dot2f(w[4 * j + 1], bch2(u.y), a1);
      a2 = dot2f(w[4 * j + 2], bch2(u.z), a2);
      a3 = dot2f(w[4 * j + 3], bch2(u.w), a3);
    }
#pragma unroll
    for (int s = 0; s < 12; ++s) {  // cols [416,512): W from LDS
      uint4 wv = wlds[s * 512 + r];
      uint4 u = hb[52 + s];
      a0 = dot2f(bch2(wv.x), bch2(u.x), a0);
      a1 = dot2f(bch2(wv.y), bch2(u.y), a1);
      a2 = dot2f(bch2(wv.z), bch2(u.z), a2);
      a3 = dot2f(bch2(wv.w), bch2(u.w), a3);
    }
    float p = (a0 + a1) + (a2 + a3);
    float hval = tanhf_fast(xwv + p);

    hs[(512 - (t & 1) * 512) + r] = (_Float16)hval;
    __syncthreads();
    xwv = xw_next;
    hval_prev = hval;
  }
  hout[(base + SS - 1) * HH + r] = (_Float16)hval_prev;
}

// out[m][c] = sum_h h1[m][h] * Wfc[c][h] + bfc[c];  one wave per row m
__global__ __launch_bounds__(256) void fc_kernel(
    const _Float16* __restrict__ h1, const float* __restrict__ Wfc,
    const float* __restrict__ bfc, float* __restrict__ out) {
  const int lane = threadIdx.x & 63;
  const int wid = threadIdx.x >> 6;
  const long m = (long)blockIdx.x * 4 + wid;
  f16x8 hv = ((const f16x8*)(h1 + m * HH))[lane];
  const float4* w0 = (const float4*)(Wfc);
  const float4* w1 = (const float4*)(Wfc + HH);
  float4 a0 = w0[2 * lane], a1 = w0[2 * lane + 1];
  float4 b0 = w1[2 * lane], b1 = w1[2 * lane + 1];
  float p0 = (float)hv[0] * a0.x + (float)hv[1] * a0.y + (float)hv[2] * a0.z +
             (float)hv[3] * a0.w + (float)hv[4] * a1.x + (float)hv[5] * a1.y +
             (float)hv[6] * a1.z + (float)hv[7] * a1.w;
  float p1 = (float)hv[0] * b0.x + (float)hv[1] * b0.y + (float)hv[2] * b0.z +
             (float)hv[3] * b0.w + (float)hv[4] * b1.x + (float)hv[5] * b1.y +
             (float)hv[6] * b1.z + (float)hv[7] * b1.w;
#pragma unroll
  for (int off = 32; off; off >>= 1) {
    p0 += __shfl_down(p0, off);
    p1 += __shfl_down(p1, off);
  }
  if (lane == 0) {
    out[m * 2 + 0] = p0 + bfc[0];
    out[m * 2 + 1] = p1 + bfc[1];
  }
}

extern "C" void kernel_launch(void* const* d_in, const int* in_sizes, int n_in,
                              void* d_out, int out_size, void* d_ws, size_t ws_size,
                              hipStream_t stream) {
  const int* tokens = (const int*)d_in[0];
  const float* emb = (const float*)d_in[1];
  const float* W_ih0 = (const float*)d_in[2];
  const float* b_ih0 = (const float*)d_in[3];
  const float* W_hh0 = (const float*)d_in[4];
  const float* b_hh0 = (const float*)d_in[5];
  const float* W_ih1 = (const float*)d_in[6];
  const float* b_ih1 = (const float*)d_in[7];
  const float* W_hh1 = (const float*)d_in[8];
  const float* b_hh1 = (const float*)d_in[9];
  const float* W_fc = (const float*)d_in[10];
  const float* b_fc = (const float*)d_in[11];
  float* out = (float*)d_out;

  const long MS = (long)BB * SS;                 // 32768
  float* bufA = (float*)d_ws;                    // xw [MS][512] f32 (64MB)
  _Float16* bufB = (_Float16*)(bufA + MS * HH);  // h  [MS][512] f16 (32MB)

  const int rec_lds = 12 * 512 * 16 + 2 * 512 * 2;  // 100352 B

  // xw0 = gather(emb, tokens) @ W_ih0^T + b_ih0 + b_hh0
  gemm_mfma<true><<<dim3(64, 4), 256, 0, stream>>>(
      nullptr, tokens, emb, W_ih0, b_ih0, b_hh0, bufA);
  // layer 0 recurrence -> h0 (f16) in bufB
  rec_v4<<<64, 512, rec_lds, stream>>>(W_hh0, bufA, bufB);
  // xw1 = h0 @ W_ih1^T + b_ih1 + b_hh1  (A = h0 f16)
  gemm_mfma<false><<<dim3(64, 4), 256, 0, stream>>>(
      bufB, nullptr, nullptr, W_ih1, b_ih1, b_hh1, bufA);
  // layer 1 recurrence -> h1 (f16) in bufB
  rec_v4<<<64, 512, rec_lds, stream>>>(W_hh1, bufA, bufB);
  // FC
  fc_kernel<<<8192, 256, 0, stream>>>(bufB, W_fc, b_fc, out);
}